// Round 1
// baseline (270.509 us; speedup 1.0000x reference)
//
#include <hip/hip_runtime.h>

#define N_OPS 32
#define D_REASON 128
#define EPS 1e-5f
#define LEAK 1e-5f
#define N_TOKENS (8 * 2048)

// ---------------------------------------------------------------------------
// Kernel 1: per-op ternary quantization.
// One block per op (32 blocks, 256 threads). Block-reduce sum(|W|), derive
// scale = max(mean|W|, EPS), then w_eff = clip(round(W/scale),-1,1)*scale.
// rintf = round-to-nearest-even, matching jnp.round / np.round semantics.
// ---------------------------------------------------------------------------
__global__ __launch_bounds__(256) void quant_kernel(const float* __restrict__ ops,
                                                    float* __restrict__ w_eff) {
    const int n = blockIdx.x;
    const float* W = ops + n * (D_REASON * D_REASON);
    float s = 0.f;
    for (int i = threadIdx.x; i < D_REASON * D_REASON; i += 256)
        s += fabsf(W[i]);
    // wave butterfly reduce (wave = 64 lanes)
    for (int off = 32; off; off >>= 1) s += __shfl_xor(s, off);
    __shared__ float red[4];
    __shared__ float s_scale;
    const int lane = threadIdx.x & 63;
    const int wid  = threadIdx.x >> 6;
    if (lane == 0) red[wid] = s;
    __syncthreads();
    if (threadIdx.x == 0) {
        float tot = red[0] + red[1] + red[2] + red[3];
        s_scale = fmaxf(tot / (float)(D_REASON * D_REASON), EPS);
    }
    __syncthreads();
    const float scale = s_scale;
    float* out = w_eff + n * (D_REASON * D_REASON);
    for (int i = threadIdx.x; i < D_REASON * D_REASON; i += 256) {
        float q = rintf(W[i] / scale);          // true divide: match ref boundary
        q = fminf(1.f, fmaxf(-1.f, q));
        out[i] = q * scale;
    }
}

// ---------------------------------------------------------------------------
// Kernel 2: fold leak term into one matrix L = (LEAK/N_OPS) * sum_n w_eff[n].
// 16384 elements, 64 blocks x 256 threads.
// ---------------------------------------------------------------------------
__global__ __launch_bounds__(256) void leak_kernel(const float* __restrict__ w_eff,
                                                   float* __restrict__ Lmat) {
    const int i = blockIdx.x * 256 + threadIdx.x;  // 0..16383
    float s = 0.f;
    for (int n = 0; n < N_OPS; ++n)
        s += w_eff[n * (D_REASON * D_REASON) + i];
    Lmat[i] = s * (LEAK / (float)N_OPS);
}

// ---------------------------------------------------------------------------
// Kernel 3: main. One wave per token (4 waves per 256-thread block).
// Lane l holds x[2l], x[2l+1]. For each output row o: coalesced float2 loads
// from L, W[i0], W[i1]; combine with routing weights; butterfly-reduce the
// dot product across the wave; lane (o&63) keeps it; two coalesced stores.
// ---------------------------------------------------------------------------
__global__ __launch_bounds__(256) void moe_kernel(const float*  __restrict__ x,
                                                  const int*    __restrict__ idx,
                                                  const float*  __restrict__ wts,
                                                  const float*  __restrict__ w_eff,
                                                  const float*  __restrict__ Lmat,
                                                  float*        __restrict__ out) {
    const int lane = threadIdx.x & 63;
    const int t    = blockIdx.x * 4 + (threadIdx.x >> 6);

    const int   i0 = idx[2 * t];
    const int   i1 = idx[2 * t + 1];
    const float w0 = wts[2 * t];
    const float w1 = wts[2 * t + 1];

    const float2  xv = ((const float2*)x)[t * 64 + lane];
    const float2* __restrict__ A0 = (const float2*)(w_eff + i0 * (D_REASON * D_REASON));
    const float2* __restrict__ A1 = (const float2*)(w_eff + i1 * (D_REASON * D_REASON));
    const float2* __restrict__ Lp = (const float2*)Lmat;

    float r0 = 0.f, r1 = 0.f;
    for (int o = 0; o < D_REASON; ++o) {
        const int off = o * 64 + lane;
        float2 lv = Lp[off];
        float2 a0 = A0[off];
        float2 a1 = A1[off];
        float cx = fmaf(w1, a1.x, fmaf(w0, a0.x, lv.x));
        float cy = fmaf(w1, a1.y, fmaf(w0, a0.y, lv.y));
        float p  = fmaf(cx, xv.x, cy * xv.y);
        // wave-wide butterfly reduction
        for (int m = 32; m; m >>= 1) p += __shfl_xor(p, m);
        if (lane == (o & 63)) {
            if (o & 64) r1 = p; else r0 = p;
        }
    }
    out[t * D_REASON + lane]      = r0;
    out[t * D_REASON + 64 + lane] = r1;
}

// ---------------------------------------------------------------------------
// Launch
// ---------------------------------------------------------------------------
extern "C" void kernel_launch(void* const* d_in, const int* in_sizes, int n_in,
                              void* d_out, int out_size, void* d_ws, size_t ws_size,
                              hipStream_t stream) {
    const float* x    = (const float*)d_in[0];
    const int*   idx  = (const int*)  d_in[1];
    const float* wts  = (const float*)d_in[2];
    const float* ops  = (const float*)d_in[3];
    float* out = (float*)d_out;

    // workspace layout: [w_eff: 32*128*128 floats][Lmat: 128*128 floats]
    float* w_eff = (float*)d_ws;
    float* Lmat  = w_eff + N_OPS * D_REASON * D_REASON;

    quant_kernel<<<N_OPS, 256, 0, stream>>>(ops, w_eff);
    leak_kernel<<<(D_REASON * D_REASON) / 256, 256, 0, stream>>>(w_eff, Lmat);
    moe_kernel<<<N_TOKENS / 4, 256, 0, stream>>>(x, idx, wts, w_eff, Lmat, out);
}